// Round 11
// baseline (519.791 us; speedup 1.0000x reference)
//
#include <hip/hip_runtime.h>

// Problem constants
#define BB    16
#define NN    729
#define DD    1152
#define HH_   16
#define HDIM  72
#define NPAD  736
#define HDPAD 96
#define MTOK  (BB*NN)   // 11664
#define ESTR  768       // attn E row stride (bf16, swizzled)

typedef __attribute__((ext_vector_type(8))) short bf16x8;
typedef __attribute__((ext_vector_type(4))) float f32x4;

__device__ __forceinline__ unsigned short f2bf(float f) {
  unsigned u = __float_as_uint(f);
  u += 0x7fffu + ((u >> 16) & 1u);
  return (unsigned short)(u >> 16);
}
__device__ __forceinline__ float bf2f(unsigned short s) {
  return __uint_as_float(((unsigned)s) << 16);
}

__device__ __forceinline__ void gload_lds16(const void* g, void* l) {
  __builtin_amdgcn_global_load_lds(
      (const __attribute__((address_space(1))) void*)(unsigned long long)g,
      (__attribute__((address_space(3))) void*)(unsigned)(unsigned long long)l,
      16, 0, 0);
}

// ---------------- cast kernels ----------------
__global__ __launch_bounds__(256) void cast_x_kernel(const float* __restrict__ in,
                                                     unsigned short* __restrict__ out, int n4) {
  int i = blockIdx.x * 256 + threadIdx.x;
  for (; i < n4; i += gridDim.x * 256) {
    float4 v = ((const float4*)in)[i];
    uint2 o;
    o.x = (unsigned)f2bf(v.x) | ((unsigned)f2bf(v.y) << 16);
    o.y = (unsigned)f2bf(v.z) | ((unsigned)f2bf(v.w) << 16);
    ((uint2*)out)[i] = o;
  }
}

__global__ __launch_bounds__(256) void cast_w_kernel(const float* __restrict__ wq,
                                                     const float* __restrict__ wk,
                                                     const float* __restrict__ wv,
                                                     const float* __restrict__ wo,
                                                     unsigned short* __restrict__ out) {
  const int per = DD * DD / 4;
  int i = blockIdx.x * 256 + threadIdx.x;
  for (; i < 4 * per; i += gridDim.x * 256) {
    const int which = i / per, off = i - which * per;
    const float* src = which == 0 ? wq : which == 1 ? wk : which == 2 ? wv : wo;
    float4 v = ((const float4*)src)[off];
    uint2 o;
    o.x = (unsigned)f2bf(v.x) | ((unsigned)f2bf(v.y) << 16);
    o.y = (unsigned)f2bf(v.z) | ((unsigned)f2bf(v.w) << 16);
    ((uint2*)out)[i] = o;
  }
}

// ---------------- log(size) table ----------------
__global__ __launch_bounds__(256) void ls_kernel(const float* __restrict__ tsize,
                                                 float* __restrict__ LSg) {
  const int idx = blockIdx.x * 256 + threadIdx.x;
  if (idx < BB * NPAD) {
    const int b = idx / NPAD, k = idx - b * NPAD;
    LSg[idx] = (k < NN) ? __logf(tsize[b * NN + k]) : -1e30f;
  }
}

// ---------------- pad-zero: Q/K hd-pads + K tail rows ----------------
__global__ __launch_bounds__(256) void pad_kernel(unsigned short* __restrict__ Qb,
                                                  unsigned short* __restrict__ Kb) {
  const int bh = blockIdx.x, t = threadIdx.x;
  unsigned short* q = Qb + (size_t)bh * NPAD * HDPAD;
  unsigned short* k = Kb + (size_t)bh * NPAD * HDPAD;
  const uint4 z = {0, 0, 0, 0};
  for (int n = t; n < NPAD; n += 256) {
    uint4* qa = (uint4*)(q + n * HDPAD + 72);
    qa[0] = z; qa[1] = z; qa[2] = z;
    uint4* ka = (uint4*)(k + n * HDPAD + 72);
    ka[0] = z; ka[1] = z; ka[2] = z;
  }
  for (int i = t; i < 7 * 36; i += 256) {
    const int r = i / 36, c = i - (i / 36) * 36;
    ((unsigned*)(k + (size_t)(729 + r) * HDPAD))[c] = 0;
  }
}

// ---------------- V repack: (b,n,1152 row-major) -> MFMA-tile-contiguous ----------------
__global__ __launch_bounds__(256) void vt_kernel(const unsigned short* __restrict__ Vtmp,
                                                 unsigned short* __restrict__ Vv) {
  __shared__ unsigned short tile[32][80];
  const int bh = blockIdx.x, kt = blockIdx.y;
  const int b = bh >> 4, hh = bh & 15;
  const int k0 = kt * 32;
  const int t = threadIdx.x;
  for (int i = t; i < 32 * 36; i += 256) {
    const int n = i / 36, c = i - (i / 36) * 36;
    unsigned u = 0;
    if (k0 + n < NN)
      u = *(const unsigned*)(Vtmp + ((size_t)(b * NN + k0 + n)) * DD + hh * HDIM + c * 2);
    tile[n][c * 2] = (unsigned short)(u & 0xffffu);
    tile[n][c * 2 + 1] = (unsigned short)(u >> 16);
  }
  for (int i = t; i < 32 * 8; i += 256) {
    const int n = i >> 3, c = i & 7;
    tile[n][72 + c] = 0;
  }
  __syncthreads();
  unsigned* dst = (unsigned*)(Vv + ((size_t)bh * 23 + kt) * 2560);
  for (int i2 = t; i2 < 1280; i2 += 256) {
    const int ni = i2 >> 8, rem = i2 & 255;
    const int lr = rem >> 4, np2 = (rem & 15) * 2;
    const int hd = ni * 16 + lr;
    const unsigned lo = tile[np2][hd], hi = tile[np2 + 1][hd];
    dst[i2] = lo | (hi << 16);
  }
}

// ---------------- 8-phase 256x256x64 GEMM ----------------
#define PH_MID() \
  __builtin_amdgcn_s_barrier(); \
  asm volatile("s_waitcnt lgkmcnt(0)" ::: "memory"); \
  __builtin_amdgcn_sched_barrier(0); \
  __builtin_amdgcn_s_setprio(1)
#define PH_END() \
  __builtin_amdgcn_s_setprio(0); \
  __builtin_amdgcn_s_barrier()
#define QUAD(MB, NB) \
  _Pragma("unroll") for (int mr = 0; mr < 4; ++mr) \
  _Pragma("unroll") for (int nr = 0; nr < 2; ++nr) \
  _Pragma("unroll") for (int s = 0; s < 2; ++s) \
    acc[(MB) + mr][(NB) + nr] = __builtin_amdgcn_mfma_f32_16x16x32_bf16( \
        a[mr][s], b[(NB) + nr][s], acc[(MB) + mr][(NB) + nr], 0, 0, 0)

template <int MODE>
__global__ __launch_bounds__(512, 2) void gemm8_kernel(
    const unsigned short* __restrict__ A,
    const unsigned short* __restrict__ Bw,
    const float* __restrict__ bi0, const float* __restrict__ bi1, const float* __restrict__ bi2,
    unsigned short* __restrict__ O0, unsigned short* __restrict__ O1, unsigned short* __restrict__ O2,
    float* __restrict__ Of, int NBX, int nlim) {
  __shared__ __align__(16) char smem[131072];
  const int tid = threadIdx.x, w = tid >> 6, l = tid & 63;
  const int lr = l & 15, lh = l >> 4;
  const int wm = w >> 2, wn = w & 3;
  const int xr = (lr & 7) << 4;

  const int nblk = gridDim.x;
  const int xc = blockIdx.x & 7, oo = blockIdx.x >> 3;
  const int qq = nblk >> 3, rr = nblk & 7;
  const int wg = (xc < rr ? xc * (qq + 1) : rr * (qq + 1) + (xc - rr) * qq) + oo;
  const int m0 = (wg % NBX) * 256;
  const int n0 = (wg / NBX) * 256;

  f32x4 acc[8][4];
  const f32x4 fz = {0.f, 0.f, 0.f, 0.f};
#pragma unroll
  for (int i = 0; i < 8; ++i)
#pragma unroll
    for (int j = 0; j < 4; ++j) acc[i][j] = fz;

  auto stage = [&](const unsigned short* mat, int rlim, int row0, int kt, char* base) {
#pragma unroll
    for (int c = 0; c < 2; ++c) {
      const int beta = w * 1024 + c * 8192 + l * 16;
      const int g = beta ^ (((beta >> 7) & 7) << 4);
      int grow = row0 + (g >> 7);
      if (grow > rlim) grow = rlim;
      gload_lds16((const char*)mat + (size_t)grow * 2304 + kt * 128 + (g & 127), base + beta);
    }
  };
  bf16x8 a[4][2], b[4][2];
  auto lda = [&](char* Ab, int mh) {
#pragma unroll
    for (int mr = 0; mr < 4; ++mr)
#pragma unroll
      for (int s = 0; s < 2; ++s) {
        const int x = (wm * 128 + mh * 64 + mr * 16 + lr) * 128 + s * 64 + lh * 16;
        a[mr][s] = *(const bf16x8*)(Ab + (x ^ xr));
      }
  };
  auto ldb = [&](char* Bb, int nh) {
#pragma unroll
    for (int nr = 0; nr < 2; ++nr)
#pragma unroll
      for (int s = 0; s < 2; ++s) {
        const int x = (wn * 64 + nh * 32 + nr * 16 + lr) * 128 + s * 64 + lh * 16;
        b[nh * 2 + nr][s] = *(const bf16x8*)(Bb + (x ^ xr));
      }
  };

  stage(A, MTOK - 1, m0, 0, smem);
  stage(A, MTOK - 1, m0 + 128, 0, smem + 16384);
  stage(Bw, nlim, n0, 0, smem + 32768);
  stage(Bw, nlim, n0 + 128, 0, smem + 49152);
  stage(A, MTOK - 1, m0, 1, smem + 65536);
  stage(A, MTOK - 1, m0 + 128, 1, smem + 81920);
  asm volatile("s_waitcnt vmcnt(4)" ::: "memory");
  __builtin_amdgcn_s_barrier();

#pragma unroll 2
  for (int k = 0; k < 18; ++k) {
    char* Ac = smem + (k & 1) * 65536;
    char* Bc = Ac + 32768;
    char* An = smem + ((k + 1) & 1) * 65536;
    char* Bn = An + 32768;
    const int kb = (k + 1 < 18) ? k + 1 : 17;
    const int ka = (k + 2 < 18) ? k + 2 : 17;
    lda(Ac, 0);
    ldb(Bc, 0);
    stage(Bw, nlim, n0, kb, Bn);
    PH_MID();
    QUAD(0, 0);
    PH_END();
    ldb(Bc, 1);
    stage(Bw, nlim, n0 + 128, kb, Bn + 16384);
    PH_MID();
    QUAD(0, 2);
    PH_END();
    lda(Ac, 1);
    PH_MID();
    QUAD(4, 2);
    PH_END();
    stage(A, MTOK - 1, m0, ka, Ac);
    stage(A, MTOK - 1, m0 + 128, ka, Ac + 16384);
    PH_MID();
    QUAD(4, 0);
    __builtin_amdgcn_s_setprio(0);
    asm volatile("s_waitcnt vmcnt(4)" ::: "memory");
    __builtin_amdgcn_s_barrier();
  }

#pragma unroll
  for (int mi = 0; mi < 8; ++mi)
#pragma unroll
    for (int ni = 0; ni < 4; ++ni) {
      const int col = n0 + wn * 64 + ni * 16 + lr;
#pragma unroll
      for (int j = 0; j < 4; ++j) {
        const int row = m0 + wm * 128 + mi * 16 + lh * 4 + j;
        if (row < MTOK) {
          float v = acc[mi][ni][j];
          if (MODE == 0) {
            if (col < 3 * DD) {
              const int which = col / DD;
              const int ec = col - which * DD;
              const float* bias = which == 0 ? bi0 : (which == 1 ? bi1 : bi2);
              v += bias[ec];
              const unsigned short bv = f2bf(v);
              if (which == 2) {
                O2[(size_t)row * DD + ec] = bv;
              } else {
                const int h = ec / HDIM, hd = ec - h * HDIM;
                const int bb = row / NN, n = row - bb * NN;
                if (which == 0)
                  O0[(((size_t)bb * HH_ + h) * NPAD + n) * HDPAD + hd] = bv;
                else
                  O1[(((size_t)bb * HH_ + h) * NPAD + n) * HDPAD + hd] = bv;
              }
            }
          } else {
            if (col < DD)
              __builtin_nontemporal_store(v + bi0[col], Of + (size_t)row * DD + col);
          }
        }
      }
    }
}

// ---------------- attention v10: K-frag pipeline + in-reg row sums ----------------
__global__ __launch_bounds__(512, 4) void attn_kernel(
    const unsigned short* __restrict__ Qb,
    const unsigned short* __restrict__ Kb,
    const unsigned short* __restrict__ Vv,
    const float* __restrict__ LSg,
    float* __restrict__ attn_out,
    unsigned short* __restrict__ Ab) {
  // Elds 49152 | INV 128 @49152 | rs 8x32 f32 @49280 -> 50304 B
  __shared__ __align__(16) char smem[50304];
  unsigned short* Elds = (unsigned short*)smem;
  float* INV = (float*)(smem + 49152);
  float* rs = (float*)(smem + 49280);
  float* red = (float*)smem;

  const int tid = threadIdx.x, w = tid >> 6, l = tid & 63;
  const int lr = l & 15, lh = l >> 4;

  const int id = blockIdx.x;
  const int nid = (id & 7) * 736 + (id >> 3);
  const int bh = nid / 23, qt = nid - bh * 23;
  const int b = bh >> 4, hh = bh & 15;
  const int q0 = qt * 32;

  const float scale = 0.11785113019775793f;  // 72^-0.5
  const size_t kvbase = (size_t)bh * NPAD * HDPAD;
  const unsigned short* qp = Qb + kvbase + (size_t)q0 * HDPAD;

  bf16x8 aq[2][3];
#pragma unroll
  for (int mi = 0; mi < 2; ++mi)
#pragma unroll
    for (int ks = 0; ks < 3; ++ks)
      aq[mi][ks] = *(const bf16x8*)(qp + (size_t)(mi * 16 + lr) * HDPAD + ks * 32 + lh * 8);

  // ---- phase 1: E = exp(QK^T*scale + LS) -> swizzled LDS; K pipelined; in-reg row sums ----
  float pp[2][4];
#pragma unroll
  for (int mi = 0; mi < 2; ++mi)
#pragma unroll
    for (int j = 0; j < 4; ++j) pp[mi][j] = 0.f;

  auto loadK = [&](int kt, bf16x8* dst) {
    const unsigned short* kp = Kb + kvbase + (size_t)(kt * 32) * HDPAD;
#pragma unroll
    for (int ks = 0; ks < 3; ++ks) {
      dst[ks * 2] = *(const bf16x8*)(kp + (size_t)lr * HDPAD + ks * 32 + lh * 8);
      dst[ks * 2 + 1] = *(const bf16x8*)(kp + (size_t)(16 + lr) * HDPAD + ks * 32 + lh * 8);
    }
  };
  auto process = [&](int kt, const bf16x8* kf) {
    const int k0 = kt * 32;
    const f32x4 fz = {0.f, 0.f, 0.f, 0.f};
    f32x4 acc[2][2];
    acc[0][0] = fz; acc[0][1] = fz; acc[1][0] = fz; acc[1][1] = fz;
#pragma unroll
    for (int ks = 0; ks < 3; ++ks) {
#pragma unroll
      for (int mi = 0; mi < 2; ++mi) {
        acc[mi][0] = __builtin_amdgcn_mfma_f32_16x16x32_bf16(aq[mi][ks], kf[ks * 2], acc[mi][0], 0, 0, 0);
        acc[mi][1] = __builtin_amdgcn_mfma_f32_16x16x32_bf16(aq[mi][ks], kf[ks * 2 + 1], acc[mi][1], 0, 0, 0);
      }
    }
#pragma unroll
    for (int ni = 0; ni < 2; ++ni) {
      const int col = k0 + ni * 16 + lr;
      const float lsv = LSg[b * NPAD + col];
#pragma unroll
      for (int mi = 0; mi < 2; ++mi)
#pragma unroll
        for (int j = 0; j < 4; ++j) {
          const int row = mi * 16 + lh * 4 + j;
          const float e = __expf(acc[mi][ni][j] * scale + lsv);
          Elds[row * ESTR + (col ^ ((row & 7) << 3))] = f2bf(e);
          pp[mi][j] += e;
        }
    }
  };

  {
    const int myc = (w < 7) ? 3 : 2;  // kt = w, w+8, w+16(<23)
    bf16x8 kfA[6], kfB[6];
    loadK(w, kfA);
    loadK(w + 8, kfB);  // always valid: w+8 <= 15 < 23
    process(w, kfA);
    if (myc > 2) loadK(w + 16, kfA);
    process(w + 8, kfB);
    if (myc > 2) process(w + 16, kfA);
  }
  // deposit per-wave row sums
  {
#pragma unroll
    for (int mi = 0; mi < 2; ++mi)
#pragma unroll
      for (int j = 0; j < 4; ++j) {
        float p = pp[mi][j];
        p += __shfl_xor(p, 1);
        p += __shfl_xor(p, 2);
        p += __shfl_xor(p, 4);
        p += __shfl_xor(p, 8);
        if (lr == 0) rs[w * 32 + mi * 16 + lh * 4 + j] = p;
      }
  }
  __syncthreads();

  // ---- fused normalize + nt write (inv from rs partials; E from LDS) ----
  const int qv = NN - q0;
  {
    const int r = tid >> 4, sub = tid & 15;
    float s = rs[r] + rs[32 + r] + rs[64 + r] + rs[96 + r] +
              rs[128 + r] + rs[160 + r] + rs[192 + r] + rs[224 + r];
    const float inv = 1.f / s;
    if (sub == 0) INV[r] = inv;
    if (r < qv) {
      const unsigned short* er = Elds + r * ESTR;
      const int sw = (r & 7) << 3;
      float* ao = attn_out + ((size_t)bh * NN + (q0 + r)) * NN;
#pragma unroll
      for (int i = 0; i < 12; ++i) {
        const int col = i * 64 + sub * 4;
        if (col + 4 <= NN) {
          const uint2 ev = *(const uint2*)(er + (col ^ sw));
          f32x4 o;
          o[0] = bf2f(ev.x & 0xffffu) * inv;
          o[1] = bf2f(ev.x >> 16) * inv;
          o[2] = bf2f(ev.y & 0xffffu) * inv;
          o[3] = bf2f(ev.y >> 16) * inv;
          __builtin_nontemporal_store(o, (f32x4*)(ao + col));
        } else if (col < NN) {
          const uint2 ev = *(const uint2*)(er + (col ^ sw));
          __builtin_nontemporal_store(bf2f(ev.x & 0xffffu) * inv, ao + col);  // col == 728
        }
      }
    }
  }

  // ---- phase 4: PV, tiled V (1KB contiguous B-frags) + double buffer ----
  const int m = w & 1, kq = w >> 1;
  const f32x4 fz = {0.f, 0.f, 0.f, 0.f};
  f32x4 acc2[5];
#pragma unroll
  for (int ni = 0; ni < 5; ++ni) acc2[ni] = fz;
  {
    const int kt0 = kq * 6, kt1 = (kq == 3) ? 23 : kt0 + 6;
    const unsigned short* vbase = Vv + (size_t)bh * 58880 + (lr * 32 + lh * 8);
    const int row = m * 16 + lr;
    const int sw = (row & 7) << 3;
    const unsigned short* erow = Elds + row * ESTR;
    bf16x8 vA[5], vB[5];
#pragma unroll
    for (int ni = 0; ni < 5; ++ni) vA[ni] = *(const bf16x8*)(vbase + (kt0 * 5 + ni) * 512);
    for (int kt = kt0; kt < kt1; kt += 2) {
      const bool h1 = (kt + 1 < kt1);
      if (h1) {
#pragma unroll
        for (int ni = 0; ni < 5; ++ni) vB[ni] = *(const bf16x8*)(vbase + ((kt + 1) * 5 + ni) * 512);
      }
      {
        const int k0 = kt * 32;
        const bf16x8 ap = *(const bf16x8*)(erow + ((k0 + lh * 8) ^ sw));
#pragma unroll
        for (int ni = 0; ni < 5; ++ni)
          acc2[ni] = __builtin_amdgcn_mfma_f32_16x16x32_bf16(ap, vA[ni], acc2[ni], 0, 0, 0);
      }
      if (h1) {
        if (kt + 2 < kt1) {
#pragma unroll
          for (int ni = 0; ni < 5; ++ni) vA[ni] = *(const bf16x8*)(vbase + ((kt + 2) * 5 + ni) * 512);
        }
        const int k0 = (kt + 1) * 32;
        const bf16x8 ap = *(const bf16x8*)(erow + ((k0 + lh * 8) ^ sw));
#pragma unroll
        for (int ni = 0; ni < 5; ++ni)
          acc2[ni] = __builtin_amdgcn_mfma_f32_16x16x32_bf16(ap, vB[ni], acc2[ni], 0, 0, 0);
      }
    }
  }
  __syncthreads();

  if (kq > 0) {
    float* rd = red + ((kq - 1) * 2 + m) * 1344;
#pragma unroll
    for (int ni = 0; ni < 5; ++ni)
#pragma unroll
      for (int j = 0; j < 4; ++j)
        rd[(lh * 4 + j) * 84 + ni * 16 + lr] = acc2[ni][j];
  }
  __syncthreads();
  if (kq == 0) {
#pragma unroll
    for (int ni = 0; ni < 5; ++ni) {
      const int d = ni * 16 + lr;
      if (d < HDIM) {
#pragma unroll
        for (int j = 0; j < 4; ++j) {
          const int rrow = m * 16 + lh * 4 + j;
          const int q = q0 + rrow;
          if (q < NN) {
            const int ro = (lh * 4 + j) * 84 + ni * 16 + lr;
            const float s2 = acc2[ni][j] + red[m * 1344 + ro] + red[(2 + m) * 1344 + ro] +
                             red[(4 + m) * 1344 + ro];
            Ab[((size_t)b * NN + q) * DD + hh * HDIM + d] = f2bf(s2 * INV[rrow]);
          }
        }
      }
    }
  }
}

// ---------------- metric ----------------
__global__ __launch_bounds__(256) void metric_kernel(const unsigned short* __restrict__ Kb,
                                                     float* __restrict__ out) {
  const int total = BB * NN * HDIM;
  int idx = blockIdx.x * 256 + threadIdx.x;
  for (; idx < total; idx += gridDim.x * 256) {
    const int b = idx / (NN * HDIM);
    const int rem = idx - b * NN * HDIM;
    const int n = rem / HDIM, d = rem - n * HDIM;
    const unsigned short* kp = Kb + (((size_t)b * HH_) * NPAD + n) * HDPAD + d;
    float s = 0.f;
#pragma unroll
    for (int h = 0; h < HH_; ++h) s += bf2f(kp[(size_t)h * NPAD * HDPAD]);
    __builtin_nontemporal_store(s * 0.0625f, out + idx);
  }
}

extern "C" void kernel_launch(void* const* d_in, const int* in_sizes, int n_in,
                              void* d_out, int out_size, void* d_ws, size_t ws_size,
                              hipStream_t stream) {
  const float* X = (const float*)d_in[0];
  const float* sz = (const float*)d_in[1];
  const float* Wq = (const float*)d_in[2];
  const float* bq = (const float*)d_in[3];
  const float* Wk = (const float*)d_in[4];
  const float* bk = (const float*)d_in[5];
  const float* Wv = (const float*)d_in[6];
  const float* bv = (const float*)d_in[7];
  const float* Wo = (const float*)d_in[8];
  const float* bo = (const float*)d_in[9];

  char* ws = (char*)d_ws;
  unsigned short* Xb = (unsigned short*)ws;                  // 11664x1152 bf16
  unsigned short* Wb = (unsigned short*)(ws + 26873856);     // 4x(1152x1152) bf16
  unsigned short* Qb = (unsigned short*)(ws + 37490688);     // (16,16,736,96)
  unsigned short* Kb = (unsigned short*)(ws + 73666560);     // (16,16,736,96)
  unsigned short* Vv = (unsigned short*)(ws + 109842432);    // (256,23,5,512) tiled V
  unsigned short* Ab = (unsigned short*)(ws + 146018304);    // 11664x1152 bf16
  unsigned short* Vtmp = Ab;                                 // V row-major (dead before attn)
  float* LSg = (float*)(ws + 172892160);                     // (16,736) fp32, dedicated

  float* out = (float*)d_out;
  float* attn = out + 13436928;
  float* metric = out + 149485824;

  ls_kernel<<<46, 256, 0, stream>>>(sz, LSg);
  cast_x_kernel<<<2048, 256, 0, stream>>>(X, Xb, 3359232);
  cast_w_kernel<<<2048, 256, 0, stream>>>(Wq, Wk, Wv, Wo, Wb);

  gemm8_kernel<0><<<644, 512, 0, stream>>>(Xb, Wb, bq, bk, bv, Qb, Kb, Vtmp, nullptr, 46, 3455);

  vt_kernel<<<dim3(256, 23), 256, 0, stream>>>(Vtmp, Vv);
  pad_kernel<<<256, 256, 0, stream>>>(Qb, Kb);
  metric_kernel<<<2048, 256, 0, stream>>>(Kb, metric);

  attn_kernel<<<5888, 512, 0, stream>>>(Qb, Kb, Vv, LSg, attn, Ab);

  gemm8_kernel<1><<<230, 512, 0, stream>>>(Ab, Wb + (size_t)3456 * 1152, bo, nullptr, nullptr,
                                           nullptr, nullptr, nullptr, out, 46, 1151);
}

// Round 12
// 493.456 us; speedup vs baseline: 1.0534x; 1.0534x over previous
//
#include <hip/hip_runtime.h>

// Problem constants
#define BB    16
#define NN    729
#define DD    1152
#define HH_   16
#define HDIM  72
#define NPAD  736
#define HDPAD 96
#define MTOK  (BB*NN)   // 11664
#define ESTR  768       // attn E row stride (bf16, swizzled)

typedef __attribute__((ext_vector_type(8))) short bf16x8;
typedef __attribute__((ext_vector_type(4))) float f32x4;

__device__ __forceinline__ unsigned short f2bf(float f) {
  unsigned u = __float_as_uint(f);
  u += 0x7fffu + ((u >> 16) & 1u);
  return (unsigned short)(u >> 16);
}
__device__ __forceinline__ float bf2f(unsigned short s) {
  return __uint_as_float(((unsigned)s) << 16);
}

__device__ __forceinline__ void gload_lds16(const void* g, void* l) {
  __builtin_amdgcn_global_load_lds(
      (const __attribute__((address_space(1))) void*)(unsigned long long)g,
      (__attribute__((address_space(3))) void*)(unsigned)(unsigned long long)l,
      16, 0, 0);
}

// ---------------- cast kernels ----------------
__global__ __launch_bounds__(256) void cast_x_kernel(const float* __restrict__ in,
                                                     unsigned short* __restrict__ out, int n4) {
  int i = blockIdx.x * 256 + threadIdx.x;
  for (; i < n4; i += gridDim.x * 256) {
    float4 v = ((const float4*)in)[i];
    uint2 o;
    o.x = (unsigned)f2bf(v.x) | ((unsigned)f2bf(v.y) << 16);
    o.y = (unsigned)f2bf(v.z) | ((unsigned)f2bf(v.w) << 16);
    ((uint2*)out)[i] = o;
  }
}

__global__ __launch_bounds__(256) void cast_w_kernel(const float* __restrict__ wq,
                                                     const float* __restrict__ wk,
                                                     const float* __restrict__ wv,
                                                     const float* __restrict__ wo,
                                                     unsigned short* __restrict__ out) {
  const int per = DD * DD / 4;
  int i = blockIdx.x * 256 + threadIdx.x;
  for (; i < 4 * per; i += gridDim.x * 256) {
    const int which = i / per, off = i - which * per;
    const float* src = which == 0 ? wq : which == 1 ? wk : which == 2 ? wv : wo;
    float4 v = ((const float4*)src)[off];
    uint2 o;
    o.x = (unsigned)f2bf(v.x) | ((unsigned)f2bf(v.y) << 16);
    o.y = (unsigned)f2bf(v.z) | ((unsigned)f2bf(v.w) << 16);
    ((uint2*)out)[i] = o;
  }
}

// ---------------- log(size) table ----------------
__global__ __launch_bounds__(256) void ls_kernel(const float* __restrict__ tsize,
                                                 float* __restrict__ LSg) {
  const int idx = blockIdx.x * 256 + threadIdx.x;
  if (idx < BB * NPAD) {
    const int b = idx / NPAD, k = idx - b * NPAD;
    LSg[idx] = (k < NN) ? __logf(tsize[b * NN + k]) : -1e30f;
  }
}

// ---------------- pad-zero: Q/K hd-pads + K tail rows ----------------
__global__ __launch_bounds__(256) void pad_kernel(unsigned short* __restrict__ Qb,
                                                  unsigned short* __restrict__ Kb) {
  const int bh = blockIdx.x, t = threadIdx.x;
  unsigned short* q = Qb + (size_t)bh * NPAD * HDPAD;
  unsigned short* k = Kb + (size_t)bh * NPAD * HDPAD;
  const uint4 z = {0, 0, 0, 0};
  for (int n = t; n < NPAD; n += 256) {
    uint4* qa = (uint4*)(q + n * HDPAD + 72);
    qa[0] = z; qa[1] = z; qa[2] = z;
    uint4* ka = (uint4*)(k + n * HDPAD + 72);
    ka[0] = z; ka[1] = z; ka[2] = z;
  }
  for (int i = t; i < 7 * 36; i += 256) {
    const int r = i / 36, c = i - (i / 36) * 36;
    ((unsigned*)(k + (size_t)(729 + r) * HDPAD))[c] = 0;
  }
}

// ---------------- V repack: (b,n,1152 row-major) -> MFMA-tile-contiguous ----------------
__global__ __launch_bounds__(256) void vt_kernel(const unsigned short* __restrict__ Vtmp,
                                                 unsigned short* __restrict__ Vv) {
  __shared__ unsigned short tile[32][80];
  const int bh = blockIdx.x, kt = blockIdx.y;
  const int b = bh >> 4, hh = bh & 15;
  const int k0 = kt * 32;
  const int t = threadIdx.x;
  for (int i = t; i < 32 * 36; i += 256) {
    const int n = i / 36, c = i - (i / 36) * 36;
    unsigned u = 0;
    if (k0 + n < NN)
      u = *(const unsigned*)(Vtmp + ((size_t)(b * NN + k0 + n)) * DD + hh * HDIM + c * 2);
    tile[n][c * 2] = (unsigned short)(u & 0xffffu);
    tile[n][c * 2 + 1] = (unsigned short)(u >> 16);
  }
  for (int i = t; i < 32 * 8; i += 256) {
    const int n = i >> 3, c = i & 7;
    tile[n][72 + c] = 0;
  }
  __syncthreads();
  unsigned* dst = (unsigned*)(Vv + ((size_t)bh * 23 + kt) * 2560);
  for (int i2 = t; i2 < 1280; i2 += 256) {
    const int ni = i2 >> 8, rem = i2 & 255;
    const int lr = rem >> 4, np2 = (rem & 15) * 2;
    const int hd = ni * 16 + lr;
    const unsigned lo = tile[np2][hd], hi = tile[np2 + 1][hd];
    dst[i2] = lo | (hi << 16);
  }
}

// ---------------- 8-phase 256x256x64 GEMM ----------------
#define PH_MID() \
  __builtin_amdgcn_s_barrier(); \
  asm volatile("s_waitcnt lgkmcnt(0)" ::: "memory"); \
  __builtin_amdgcn_sched_barrier(0); \
  __builtin_amdgcn_s_setprio(1)
#define PH_END() \
  __builtin_amdgcn_s_setprio(0); \
  __builtin_amdgcn_s_barrier()
#define QUAD(MB, NB) \
  _Pragma("unroll") for (int mr = 0; mr < 4; ++mr) \
  _Pragma("unroll") for (int nr = 0; nr < 2; ++nr) \
  _Pragma("unroll") for (int s = 0; s < 2; ++s) \
    acc[(MB) + mr][(NB) + nr] = __builtin_amdgcn_mfma_f32_16x16x32_bf16( \
        a[mr][s], b[(NB) + nr][s], acc[(MB) + mr][(NB) + nr], 0, 0, 0)

template <int MODE>
__global__ __launch_bounds__(512, 2) void gemm8_kernel(
    const unsigned short* __restrict__ A,
    const unsigned short* __restrict__ Bw,
    const float* __restrict__ bi0, const float* __restrict__ bi1, const float* __restrict__ bi2,
    unsigned short* __restrict__ O0, unsigned short* __restrict__ O1, unsigned short* __restrict__ O2,
    float* __restrict__ Of, int NBX, int nlim) {
  __shared__ __align__(16) char smem[131072];
  const int tid = threadIdx.x, w = tid >> 6, l = tid & 63;
  const int lr = l & 15, lh = l >> 4;
  const int wm = w >> 2, wn = w & 3;
  const int xr = (lr & 7) << 4;

  const int nblk = gridDim.x;
  const int xc = blockIdx.x & 7, oo = blockIdx.x >> 3;
  const int qq = nblk >> 3, rr = nblk & 7;
  const int wg = (xc < rr ? xc * (qq + 1) : rr * (qq + 1) + (xc - rr) * qq) + oo;
  const int m0 = (wg % NBX) * 256;
  const int n0 = (wg / NBX) * 256;

  f32x4 acc[8][4];
  const f32x4 fz = {0.f, 0.f, 0.f, 0.f};
#pragma unroll
  for (int i = 0; i < 8; ++i)
#pragma unroll
    for (int j = 0; j < 4; ++j) acc[i][j] = fz;

  auto stage = [&](const unsigned short* mat, int rlim, int row0, int kt, char* base) {
#pragma unroll
    for (int c = 0; c < 2; ++c) {
      const int beta = w * 1024 + c * 8192 + l * 16;
      const int g = beta ^ (((beta >> 7) & 7) << 4);
      int grow = row0 + (g >> 7);
      if (grow > rlim) grow = rlim;
      gload_lds16((const char*)mat + (size_t)grow * 2304 + kt * 128 + (g & 127), base + beta);
    }
  };
  bf16x8 a[4][2], b[4][2];
  auto lda = [&](char* Ab, int mh) {
#pragma unroll
    for (int mr = 0; mr < 4; ++mr)
#pragma unroll
      for (int s = 0; s < 2; ++s) {
        const int x = (wm * 128 + mh * 64 + mr * 16 + lr) * 128 + s * 64 + lh * 16;
        a[mr][s] = *(const bf16x8*)(Ab + (x ^ xr));
      }
  };
  auto ldb = [&](char* Bb, int nh) {
#pragma unroll
    for (int nr = 0; nr < 2; ++nr)
#pragma unroll
      for (int s = 0; s < 2; ++s) {
        const int x = (wn * 64 + nh * 32 + nr * 16 + lr) * 128 + s * 64 + lh * 16;
        b[nh * 2 + nr][s] = *(const bf16x8*)(Bb + (x ^ xr));
      }
  };

  stage(A, MTOK - 1, m0, 0, smem);
  stage(A, MTOK - 1, m0 + 128, 0, smem + 16384);
  stage(Bw, nlim, n0, 0, smem + 32768);
  stage(Bw, nlim, n0 + 128, 0, smem + 49152);
  stage(A, MTOK - 1, m0, 1, smem + 65536);
  stage(A, MTOK - 1, m0 + 128, 1, smem + 81920);
  asm volatile("s_waitcnt vmcnt(4)" ::: "memory");
  __builtin_amdgcn_s_barrier();

#pragma unroll 2
  for (int k = 0; k < 18; ++k) {
    char* Ac = smem + (k & 1) * 65536;
    char* Bc = Ac + 32768;
    char* An = smem + ((k + 1) & 1) * 65536;
    char* Bn = An + 32768;
    const int kb = (k + 1 < 18) ? k + 1 : 17;
    const int ka = (k + 2 < 18) ? k + 2 : 17;
    lda(Ac, 0);
    ldb(Bc, 0);
    stage(Bw, nlim, n0, kb, Bn);
    PH_MID();
    QUAD(0, 0);
    PH_END();
    ldb(Bc, 1);
    stage(Bw, nlim, n0 + 128, kb, Bn + 16384);
    PH_MID();
    QUAD(0, 2);
    PH_END();
    lda(Ac, 1);
    PH_MID();
    QUAD(4, 2);
    PH_END();
    stage(A, MTOK - 1, m0, ka, Ac);
    stage(A, MTOK - 1, m0 + 128, ka, Ac + 16384);
    PH_MID();
    QUAD(4, 0);
    __builtin_amdgcn_s_setprio(0);
    asm volatile("s_waitcnt vmcnt(4)" ::: "memory");
    __builtin_amdgcn_s_barrier();
  }

#pragma unroll
  for (int mi = 0; mi < 8; ++mi)
#pragma unroll
    for (int ni = 0; ni < 4; ++ni) {
      const int col = n0 + wn * 64 + ni * 16 + lr;
#pragma unroll
      for (int j = 0; j < 4; ++j) {
        const int row = m0 + wm * 128 + mi * 16 + lh * 4 + j;
        if (row < MTOK) {
          float v = acc[mi][ni][j];
          if (MODE == 0) {
            if (col < 3 * DD) {
              const int which = col / DD;
              const int ec = col - which * DD;
              const float* bias = which == 0 ? bi0 : (which == 1 ? bi1 : bi2);
              v += bias[ec];
              const unsigned short bv = f2bf(v);
              if (which == 2) {
                O2[(size_t)row * DD + ec] = bv;
              } else {
                const int h = ec / HDIM, hd = ec - h * HDIM;
                const int bb = row / NN, n = row - bb * NN;
                if (which == 0)
                  O0[(((size_t)bb * HH_ + h) * NPAD + n) * HDPAD + hd] = bv;
                else
                  O1[(((size_t)bb * HH_ + h) * NPAD + n) * HDPAD + hd] = bv;
              }
            }
          } else {
            if (col < DD)
              __builtin_nontemporal_store(v + bi0[col], Of + (size_t)row * DD + col);
          }
        }
      }
    }
}

// ---------------- attention v11: R10 structure + bh-parity phase stagger ----------------
__global__ __launch_bounds__(512, 4) void attn_kernel(
    const unsigned short* __restrict__ Qb,
    const unsigned short* __restrict__ Kb,
    const unsigned short* __restrict__ Vv,
    const float* __restrict__ LSg,
    float* __restrict__ attn_out,
    unsigned short* __restrict__ Ab) {
  __shared__ __align__(16) char smem[49280];
  unsigned short* Elds = (unsigned short*)smem;
  float* INV = (float*)(smem + 49152);
  float* red = (float*)smem;

  const int tid = threadIdx.x, w = tid >> 6, l = tid & 63;
  const int lr = l & 15, lh = l >> 4;

  const int id = blockIdx.x;
  const int nid = (id & 7) * 736 + (id >> 3);
  const int bh = nid / 23, qt = nid - bh * 23;
  const int b = bh >> 4, hh = bh & 15;
  const int q0 = qt * 32;

  const float scale = 0.11785113019775793f;  // 72^-0.5
  const size_t kvbase = (size_t)bh * NPAD * HDPAD;
  const unsigned short* qp = Qb + kvbase + (size_t)q0 * HDPAD;

  bf16x8 aq[2][3];
#pragma unroll
  for (int mi = 0; mi < 2; ++mi)
#pragma unroll
    for (int ks = 0; ks < 3; ++ks)
      aq[mi][ks] = *(const bf16x8*)(qp + (size_t)(mi * 16 + lr) * HDPAD + ks * 32 + lh * 8);

  // ---- phase 1: E = exp(QK^T*scale + LS) -> swizzled LDS ----
  for (int kt = w; kt < 23; kt += 8) {
    const int k0 = kt * 32;
    const f32x4 fz = {0.f, 0.f, 0.f, 0.f};
    f32x4 acc[2][2];
    acc[0][0] = fz; acc[0][1] = fz; acc[1][0] = fz; acc[1][1] = fz;
    const unsigned short* kp = Kb + kvbase + (size_t)k0 * HDPAD;
#pragma unroll
    for (int ks = 0; ks < 3; ++ks) {
      const bf16x8 bk0 = *(const bf16x8*)(kp + (size_t)lr * HDPAD + ks * 32 + lh * 8);
      const bf16x8 bk1 = *(const bf16x8*)(kp + (size_t)(16 + lr) * HDPAD + ks * 32 + lh * 8);
#pragma unroll
      for (int mi = 0; mi < 2; ++mi) {
        acc[mi][0] = __builtin_amdgcn_mfma_f32_16x16x32_bf16(aq[mi][ks], bk0, acc[mi][0], 0, 0, 0);
        acc[mi][1] = __builtin_amdgcn_mfma_f32_16x16x32_bf16(aq[mi][ks], bk1, acc[mi][1], 0, 0, 0);
      }
    }
#pragma unroll
    for (int ni = 0; ni < 2; ++ni) {
      const int col = k0 + ni * 16 + lr;
      const float lsv = LSg[b * NPAD + col];
#pragma unroll
      for (int mi = 0; mi < 2; ++mi)
#pragma unroll
        for (int j = 0; j < 4; ++j) {
          const int row = mi * 16 + lh * 4 + j;
          const int swcol = col ^ ((row & 7) << 3);
          Elds[row * ESTR + swcol] = f2bf(__expf(acc[mi][ni][j] * scale + lsv));
        }
    }
  }
  __syncthreads();

  const int qv = NN - q0;
  const int m = w & 1, kq = w >> 1;
  const f32x4 fz = {0.f, 0.f, 0.f, 0.f};
  f32x4 acc2[5];
#pragma unroll
  for (int ni = 0; ni < 5; ++ni) acc2[ni] = fz;

  // fused row-sum + normalized nt write (E kept in registers)
  auto norm_write = [&]() {
    const int r = tid >> 4, sub = tid & 15;
    const unsigned short* er = Elds + r * ESTR;
    const int sw = (r & 7) << 3;
    uint2 ev[12];
    float s = 0.f;
#pragma unroll
    for (int i = 0; i < 12; ++i) {
      const int col = i * 64 + sub * 4;
      if (col < NPAD) {
        ev[i] = *(const uint2*)(er + (col ^ sw));
        s += bf2f(ev[i].x & 0xffffu) + bf2f(ev[i].x >> 16) +
             bf2f(ev[i].y & 0xffffu) + bf2f(ev[i].y >> 16);
      }
    }
#pragma unroll
    for (int o = 1; o < 16; o <<= 1) s += __shfl_xor(s, o);
    const float inv = 1.f / s;
    if (sub == 0) INV[r] = inv;
    if (r < qv) {
      float* ao = attn_out + ((size_t)bh * NN + (q0 + r)) * NN;
#pragma unroll
      for (int i = 0; i < 12; ++i) {
        const int col = i * 64 + sub * 4;
        if (col + 4 <= NN) {
          f32x4 o;
          o[0] = bf2f(ev[i].x & 0xffffu) * inv;
          o[1] = bf2f(ev[i].x >> 16) * inv;
          o[2] = bf2f(ev[i].y & 0xffffu) * inv;
          o[3] = bf2f(ev[i].y >> 16) * inv;
          __builtin_nontemporal_store(o, (f32x4*)(ao + col));
        } else if (col < NN) {
          __builtin_nontemporal_store(bf2f(ev[i].x & 0xffffu) * inv, ao + col);  // col == 728
        }
      }
    }
  };

  // PV with tiled V (1KB contiguous B-frags) + double buffer
  auto pv = [&]() {
    const int kt0 = kq * 6, kt1 = (kq == 3) ? 23 : kt0 + 6;
    const unsigned short* vbase = Vv + (size_t)bh * 58880 + (lr * 32 + lh * 8);
    const int row = m * 16 + lr;
    const int sw = (row & 7) << 3;
    const unsigned short* erow = Elds + row * ESTR;
    bf16x8 vA[5], vB[5];
#pragma unroll
    for (int ni = 0; ni < 5; ++ni) vA[ni] = *(const bf16x8*)(vbase + (kt0 * 5 + ni) * 512);
    for (int kt = kt0; kt < kt1; kt += 2) {
      const bool h1 = (kt + 1 < kt1);
      if (h1) {
#pragma unroll
        for (int ni = 0; ni < 5; ++ni) vB[ni] = *(const bf16x8*)(vbase + ((kt + 1) * 5 + ni) * 512);
      }
      {
        const int k0 = kt * 32;
        const bf16x8 ap = *(const bf16x8*)(erow + ((k0 + lh * 8) ^ sw));
#pragma unroll
        for (int ni = 0; ni < 5; ++ni)
          acc2[ni] = __builtin_amdgcn_mfma_f32_16x16x32_bf16(ap, vA[ni], acc2[ni], 0, 0, 0);
      }
      if (h1) {
        if (kt + 2 < kt1) {
#pragma unroll
          for (int ni = 0; ni < 5; ++ni) vA[ni] = *(const bf16x8*)(vbase + ((kt + 2) * 5 + ni) * 512);
        }
        const int k0 = (kt + 1) * 32;
        const bf16x8 ap = *(const bf16x8*)(erow + ((k0 + lh * 8) ^ sw));
#pragma unroll
        for (int ni = 0; ni < 5; ++ni)
          acc2[ni] = __builtin_amdgcn_mfma_f32_16x16x32_bf16(ap, vB[ni], acc2[ni], 0, 0, 0);
      }
    }
  };

  // bh-parity stagger: half the WGs write first, half compute first
  if (bh & 1) {
    norm_write();
    pv();
  } else {
    pv();
    norm_write();
  }
  __syncthreads();

  if (kq > 0) {
    float* rd = red + ((kq - 1) * 2 + m) * 1344;
#pragma unroll
    for (int ni = 0; ni < 5; ++ni)
#pragma unroll
      for (int j = 0; j < 4; ++j)
        rd[(lh * 4 + j) * 84 + ni * 16 + lr] = acc2[ni][j];
  }
  __syncthreads();
  if (kq == 0) {
#pragma unroll
    for (int ni = 0; ni < 5; ++ni) {
      const int d = ni * 16 + lr;
      if (d < HDIM) {
#pragma unroll
        for (int j = 0; j < 4; ++j) {
          const int rrow = m * 16 + lh * 4 + j;
          const int q = q0 + rrow;
          if (q < NN) {
            const int ro = (lh * 4 + j) * 84 + ni * 16 + lr;
            const float s2 = acc2[ni][j] + red[m * 1344 + ro] + red[(2 + m) * 1344 + ro] +
                             red[(4 + m) * 1344 + ro];
            Ab[((size_t)b * NN + q) * DD + hh * HDIM + d] = f2bf(s2 * INV[rrow]);
          }
        }
      }
    }
  }
}

// ---------------- metric ----------------
__global__ __launch_bounds__(256) void metric_kernel(const unsigned short* __restrict__ Kb,
                                                     float* __restrict__ out) {
  const int total = BB * NN * HDIM;
  int idx = blockIdx.x * 256 + threadIdx.x;
  for (; idx < total; idx += gridDim.x * 256) {
    const int b = idx / (NN * HDIM);
    const int rem = idx - b * NN * HDIM;
    const int n = rem / HDIM, d = rem - n * HDIM;
    const unsigned short* kp = Kb + (((size_t)b * HH_) * NPAD + n) * HDPAD + d;
    float s = 0.f;
#pragma unroll
    for (int h = 0; h < HH_; ++h) s += bf2f(kp[(size_t)h * NPAD * HDPAD]);
    __builtin_nontemporal_store(s * 0.0625f, out + idx);
  }
}

extern "C" void kernel_launch(void* const* d_in, const int* in_sizes, int n_in,
                              void* d_out, int out_size, void* d_ws, size_t ws_size,
                              hipStream_t stream) {
  const float* X = (const float*)d_in[0];
  const float* sz = (const float*)d_in[1];
  const float* Wq = (const float*)d_in[2];
  const float* bq = (const float*)d_in[3];
  const float* Wk = (const float*)d_in[4];
  const float* bk = (const float*)d_in[5];
  const float* Wv = (const float*)d_in[6];
  const float* bv = (const float*)d_in[7];
  const float* Wo = (const float*)d_in[8];
  const float* bo = (const float*)d_in[9];

  char* ws = (char*)d_ws;
  unsigned short* Xb = (unsigned short*)ws;                  // 11664x1152 bf16
  unsigned short* Wb = (unsigned short*)(ws + 26873856);     // 4x(1152x1152) bf16
  unsigned short* Qb = (unsigned short*)(ws + 37490688);     // (16,16,736,96)
  unsigned short* Kb = (unsigned short*)(ws + 73666560);     // (16,16,736,96)
  unsigned short* Vv = (unsigned short*)(ws + 109842432);    // (256,23,5,512) tiled V
  unsigned short* Ab = (unsigned short*)(ws + 146018304);    // 11664x1152 bf16
  unsigned short* Vtmp = Ab;                                 // V row-major (dead before attn)
  float* LSg = (float*)(ws + 172892160);                     // (16,736) fp32, dedicated

  float* out = (float*)d_out;
  float* attn = out + 13436928;
  float* metric = out + 149485824;

  ls_kernel<<<46, 256, 0, stream>>>(sz, LSg);
  cast_x_kernel<<<2048, 256, 0, stream>>>(X, Xb, 3359232);
  cast_w_kernel<<<2048, 256, 0, stream>>>(Wq, Wk, Wv, Wo, Wb);

  gemm8_kernel<0><<<644, 512, 0, stream>>>(Xb, Wb, bq, bk, bv, Qb, Kb, Vtmp, nullptr, 46, 3455);

  vt_kernel<<<dim3(256, 23), 256, 0, stream>>>(Vtmp, Vv);
  pad_kernel<<<256, 256, 0, stream>>>(Qb, Kb);
  metric_kernel<<<2048, 256, 0, stream>>>(Kb, metric);

  attn_kernel<<<5888, 512, 0, stream>>>(Qb, Kb, Vv, LSg, attn, Ab);

  gemm8_kernel<1><<<230, 512, 0, stream>>>(Ab, Wb + (size_t)3456 * 1152, bo, nullptr, nullptr,
                                           nullptr, nullptr, nullptr, out, 46, 1151);
}

// Round 13
// 483.297 us; speedup vs baseline: 1.0755x; 1.0210x over previous
//
#include <hip/hip_runtime.h>

// Problem constants
#define BB    16
#define NN    729
#define DD    1152
#define HH_   16
#define HDIM  72
#define NPAD  736
#define HDPAD 96
#define MTOK  (BB*NN)   // 11664
#define ESTR  768       // attn E row stride (bf16, swizzled)

typedef __attribute__((ext_vector_type(8))) short bf16x8;
typedef __attribute__((ext_vector_type(4))) float f32x4;

__device__ __forceinline__ unsigned short f2bf(float f) {
  unsigned u = __float_as_uint(f);
  u += 0x7fffu + ((u >> 16) & 1u);
  return (unsigned short)(u >> 16);
}
__device__ __forceinline__ float bf2f(unsigned short s) {
  return __uint_as_float(((unsigned)s) << 16);
}

__device__ __forceinline__ void gload_lds16(const void* g, void* l) {
  __builtin_amdgcn_global_load_lds(
      (const __attribute__((address_space(1))) void*)(unsigned long long)g,
      (__attribute__((address_space(3))) void*)(unsigned)(unsigned long long)l,
      16, 0, 0);
}

// ---------------- prep: log-size table + X cast + W cast (fused) ----------------
__global__ __launch_bounds__(256) void prep_kernel(
    const float* __restrict__ X, const float* __restrict__ wq, const float* __restrict__ wk,
    const float* __restrict__ wv, const float* __restrict__ wo, const float* __restrict__ tsize,
    unsigned short* __restrict__ Xb, unsigned short* __restrict__ Wb, float* __restrict__ LSg) {
  const int NX = 3359232;   // X float4/uint2 items
  const int NW = 1327104;   // 4 x 331776 W items
  const int NL = BB * NPAD; // 11776
  const int total = NX + NW + NL;
  int i = blockIdx.x * 256 + threadIdx.x;
  for (; i < total; i += gridDim.x * 256) {
    if (i < NX) {
      float4 v = ((const float4*)X)[i];
      uint2 o;
      o.x = (unsigned)f2bf(v.x) | ((unsigned)f2bf(v.y) << 16);
      o.y = (unsigned)f2bf(v.z) | ((unsigned)f2bf(v.w) << 16);
      ((uint2*)Xb)[i] = o;
    } else if (i < NX + NW) {
      const int j = i - NX;
      const int per = 331776;
      const int which = j / per, off = j - which * per;
      const float* src = which == 0 ? wq : which == 1 ? wk : which == 2 ? wv : wo;
      float4 v = ((const float4*)src)[off];
      uint2 o;
      o.x = (unsigned)f2bf(v.x) | ((unsigned)f2bf(v.y) << 16);
      o.y = (unsigned)f2bf(v.z) | ((unsigned)f2bf(v.w) << 16);
      ((uint2*)Wb)[j] = o;
    } else {
      const int j = i - NX - NW;
      const int b = j / NPAD, k = j - b * NPAD;
      LSg[j] = (k < NN) ? __logf(tsize[b * NN + k]) : -1e30f;
    }
  }
}

// ---------------- post: V repack + Q/K pad-zero + metric (fused by block range) ----------------
// blocks [0,5888): vt role (bh = bid/23, kt = bid%23)
// blocks [5888,6144): pad role (bh = bid-5888)
// blocks [6144,8192): metric role (grid-stride, 2048 blocks)
__global__ __launch_bounds__(256) void post_kernel(
    const unsigned short* __restrict__ Vtmp, unsigned short* __restrict__ Vv,
    unsigned short* __restrict__ Qb, unsigned short* __restrict__ Kb,
    float* __restrict__ metric) {
  __shared__ unsigned short tile[32][80];
  const int bid = blockIdx.x, t = threadIdx.x;
  if (bid < 5888) {
    const int bh = bid / 23, kt = bid - (bid / 23) * 23;
    const int b = bh >> 4, hh = bh & 15;
    const int k0 = kt * 32;
    for (int i = t; i < 32 * 36; i += 256) {
      const int n = i / 36, c = i - (i / 36) * 36;
      unsigned u = 0;
      if (k0 + n < NN)
        u = *(const unsigned*)(Vtmp + ((size_t)(b * NN + k0 + n)) * DD + hh * HDIM + c * 2);
      tile[n][c * 2] = (unsigned short)(u & 0xffffu);
      tile[n][c * 2 + 1] = (unsigned short)(u >> 16);
    }
    for (int i = t; i < 32 * 8; i += 256) {
      const int n = i >> 3, c = i & 7;
      tile[n][72 + c] = 0;
    }
    __syncthreads();
    unsigned* dst = (unsigned*)(Vv + ((size_t)bh * 23 + kt) * 2560);
    for (int i2 = t; i2 < 1280; i2 += 256) {
      const int ni = i2 >> 8, rem = i2 & 255;
      const int lr = rem >> 4, np2 = (rem & 15) * 2;
      const int hd = ni * 16 + lr;
      const unsigned lo = tile[np2][hd], hi = tile[np2 + 1][hd];
      dst[i2] = lo | (hi << 16);
    }
  } else if (bid < 6144) {
    const int bh = bid - 5888;
    unsigned short* q = Qb + (size_t)bh * NPAD * HDPAD;
    unsigned short* k = Kb + (size_t)bh * NPAD * HDPAD;
    const uint4 z = {0, 0, 0, 0};
    for (int n = t; n < NPAD; n += 256) {
      uint4* qa = (uint4*)(q + n * HDPAD + 72);
      qa[0] = z; qa[1] = z; qa[2] = z;
      uint4* ka = (uint4*)(k + n * HDPAD + 72);
      ka[0] = z; ka[1] = z; ka[2] = z;
    }
    for (int i = t; i < 7 * 36; i += 256) {
      const int r = i / 36, c = i - (i / 36) * 36;
      ((unsigned*)(k + (size_t)(729 + r) * HDPAD))[c] = 0;
    }
  } else {
    const int total = BB * NN * HDIM;
    int idx = (bid - 6144) * 256 + t;
    for (; idx < total; idx += 2048 * 256) {
      const int b = idx / (NN * HDIM);
      const int rem = idx - b * NN * HDIM;
      const int n = rem / HDIM, d = rem - n * HDIM;
      const unsigned short* kp = Kb + (((size_t)b * HH_) * NPAD + n) * HDPAD + d;
      float s = 0.f;
#pragma unroll
      for (int h = 0; h < HH_; ++h) s += bf2f(kp[(size_t)h * NPAD * HDPAD]);
      __builtin_nontemporal_store(s * 0.0625f, metric + idx);
    }
  }
}

// ---------------- 8-phase 256x256x64 GEMM ----------------
#define PH_MID() \
  __builtin_amdgcn_s_barrier(); \
  asm volatile("s_waitcnt lgkmcnt(0)" ::: "memory"); \
  __builtin_amdgcn_sched_barrier(0); \
  __builtin_amdgcn_s_setprio(1)
#define PH_END() \
  __builtin_amdgcn_s_setprio(0); \
  __builtin_amdgcn_s_barrier()
#define QUAD(MB, NB) \
  _Pragma("unroll") for (int mr = 0; mr < 4; ++mr) \
  _Pragma("unroll") for (int nr = 0; nr < 2; ++nr) \
  _Pragma("unroll") for (int s = 0; s < 2; ++s) \
    acc[(MB) + mr][(NB) + nr] = __builtin_amdgcn_mfma_f32_16x16x32_bf16( \
        a[mr][s], b[(NB) + nr][s], acc[(MB) + mr][(NB) + nr], 0, 0, 0)

template <int MODE>
__global__ __launch_bounds__(512, 2) void gemm8_kernel(
    const unsigned short* __restrict__ A,
    const unsigned short* __restrict__ Bw,
    const float* __restrict__ bi0, const float* __restrict__ bi1, const float* __restrict__ bi2,
    unsigned short* __restrict__ O0, unsigned short* __restrict__ O1, unsigned short* __restrict__ O2,
    float* __restrict__ Of, int NBX, int nlim) {
  __shared__ __align__(16) char smem[131072];
  const int tid = threadIdx.x, w = tid >> 6, l = tid & 63;
  const int lr = l & 15, lh = l >> 4;
  const int wm = w >> 2, wn = w & 3;
  const int xr = (lr & 7) << 4;

  const int nblk = gridDim.x;
  const int xc = blockIdx.x & 7, oo = blockIdx.x >> 3;
  const int qq = nblk >> 3, rr = nblk & 7;
  const int wg = (xc < rr ? xc * (qq + 1) : rr * (qq + 1) + (xc - rr) * qq) + oo;
  const int m0 = (wg % NBX) * 256;
  const int n0 = (wg / NBX) * 256;

  f32x4 acc[8][4];
  const f32x4 fz = {0.f, 0.f, 0.f, 0.f};
#pragma unroll
  for (int i = 0; i < 8; ++i)
#pragma unroll
    for (int j = 0; j < 4; ++j) acc[i][j] = fz;

  auto stage = [&](const unsigned short* mat, int rlim, int row0, int kt, char* base) {
#pragma unroll
    for (int c = 0; c < 2; ++c) {
      const int beta = w * 1024 + c * 8192 + l * 16;
      const int g = beta ^ (((beta >> 7) & 7) << 4);
      int grow = row0 + (g >> 7);
      if (grow > rlim) grow = rlim;
      gload_lds16((const char*)mat + (size_t)grow * 2304 + kt * 128 + (g & 127), base + beta);
    }
  };
  bf16x8 a[4][2], b[4][2];
  auto lda = [&](char* Ab, int mh) {
#pragma unroll
    for (int mr = 0; mr < 4; ++mr)
#pragma unroll
      for (int s = 0; s < 2; ++s) {
        const int x = (wm * 128 + mh * 64 + mr * 16 + lr) * 128 + s * 64 + lh * 16;
        a[mr][s] = *(const bf16x8*)(Ab + (x ^ xr));
      }
  };
  auto ldb = [&](char* Bb, int nh) {
#pragma unroll
    for (int nr = 0; nr < 2; ++nr)
#pragma unroll
      for (int s = 0; s < 2; ++s) {
        const int x = (wn * 64 + nh * 32 + nr * 16 + lr) * 128 + s * 64 + lh * 16;
        b[nh * 2 + nr][s] = *(const bf16x8*)(Bb + (x ^ xr));
      }
  };

  stage(A, MTOK - 1, m0, 0, smem);
  stage(A, MTOK - 1, m0 + 128, 0, smem + 16384);
  stage(Bw, nlim, n0, 0, smem + 32768);
  stage(Bw, nlim, n0 + 128, 0, smem + 49152);
  stage(A, MTOK - 1, m0, 1, smem + 65536);
  stage(A, MTOK - 1, m0 + 128, 1, smem + 81920);
  asm volatile("s_waitcnt vmcnt(4)" ::: "memory");
  __builtin_amdgcn_s_barrier();

#pragma unroll 2
  for (int k = 0; k < 18; ++k) {
    char* Ac = smem + (k & 1) * 65536;
    char* Bc = Ac + 32768;
    char* An = smem + ((k + 1) & 1) * 65536;
    char* Bn = An + 32768;
    const int kb = (k + 1 < 18) ? k + 1 : 17;
    const int ka = (k + 2 < 18) ? k + 2 : 17;
    lda(Ac, 0);
    ldb(Bc, 0);
    stage(Bw, nlim, n0, kb, Bn);
    PH_MID();
    QUAD(0, 0);
    PH_END();
    ldb(Bc, 1);
    stage(Bw, nlim, n0 + 128, kb, Bn + 16384);
    PH_MID();
    QUAD(0, 2);
    PH_END();
    lda(Ac, 1);
    PH_MID();
    QUAD(4, 2);
    PH_END();
    stage(A, MTOK - 1, m0, ka, Ac);
    stage(A, MTOK - 1, m0 + 128, ka, Ac + 16384);
    PH_MID();
    QUAD(4, 0);
    __builtin_amdgcn_s_setprio(0);
    asm volatile("s_waitcnt vmcnt(4)" ::: "memory");
    __builtin_amdgcn_s_barrier();
  }

#pragma unroll
  for (int mi = 0; mi < 8; ++mi)
#pragma unroll
    for (int ni = 0; ni < 4; ++ni) {
      const int col = n0 + wn * 64 + ni * 16 + lr;
#pragma unroll
      for (int j = 0; j < 4; ++j) {
        const int row = m0 + wm * 128 + mi * 16 + lh * 4 + j;
        if (row < MTOK) {
          float v = acc[mi][ni][j];
          if (MODE == 0) {
            if (col < 3 * DD) {
              const int which = col / DD;
              const int ec = col - which * DD;
              const float* bias = which == 0 ? bi0 : (which == 1 ? bi1 : bi2);
              v += bias[ec];
              const unsigned short bv = f2bf(v);
              if (which == 2) {
                O2[(size_t)row * DD + ec] = bv;
              } else {
                const int h = ec / HDIM, hd = ec - h * HDIM;
                const int bb = row / NN, n = row - bb * NN;
                if (which == 0)
                  O0[(((size_t)bb * HH_ + h) * NPAD + n) * HDPAD + hd] = bv;
                else
                  O1[(((size_t)bb * HH_ + h) * NPAD + n) * HDPAD + hd] = bv;
              }
            }
          } else {
            if (col < DD)
              __builtin_nontemporal_store(v + bi0[col], Of + (size_t)row * DD + col);
          }
        }
      }
    }
}

// ---------------- attention v11: R10 structure + bh-parity phase stagger ----------------
__global__ __launch_bounds__(512, 4) void attn_kernel(
    const unsigned short* __restrict__ Qb,
    const unsigned short* __restrict__ Kb,
    const unsigned short* __restrict__ Vv,
    const float* __restrict__ LSg,
    float* __restrict__ attn_out,
    unsigned short* __restrict__ Ab) {
  __shared__ __align__(16) char smem[49280];
  unsigned short* Elds = (unsigned short*)smem;
  float* INV = (float*)(smem + 49152);
  float* red = (float*)smem;

  const int tid = threadIdx.x, w = tid >> 6, l = tid & 63;
  const int lr = l & 15, lh = l >> 4;

  const int id = blockIdx.x;
  const int nid = (id & 7) * 736 + (id >> 3);
  const int bh = nid / 23, qt = nid - bh * 23;
  const int b = bh >> 4, hh = bh & 15;
  const int q0 = qt * 32;

  const float scale = 0.11785113019775793f;  // 72^-0.5
  const size_t kvbase = (size_t)bh * NPAD * HDPAD;
  const unsigned short* qp = Qb + kvbase + (size_t)q0 * HDPAD;

  bf16x8 aq[2][3];
#pragma unroll
  for (int mi = 0; mi < 2; ++mi)
#pragma unroll
    for (int ks = 0; ks < 3; ++ks)
      aq[mi][ks] = *(const bf16x8*)(qp + (size_t)(mi * 16 + lr) * HDPAD + ks * 32 + lh * 8);

  // ---- phase 1: E = exp(QK^T*scale + LS) -> swizzled LDS ----
  for (int kt = w; kt < 23; kt += 8) {
    const int k0 = kt * 32;
    const f32x4 fz = {0.f, 0.f, 0.f, 0.f};
    f32x4 acc[2][2];
    acc[0][0] = fz; acc[0][1] = fz; acc[1][0] = fz; acc[1][1] = fz;
    const unsigned short* kp = Kb + kvbase + (size_t)k0 * HDPAD;
#pragma unroll
    for (int ks = 0; ks < 3; ++ks) {
      const bf16x8 bk0 = *(const bf16x8*)(kp + (size_t)lr * HDPAD + ks * 32 + lh * 8);
      const bf16x8 bk1 = *(const bf16x8*)(kp + (size_t)(16 + lr) * HDPAD + ks * 32 + lh * 8);
#pragma unroll
      for (int mi = 0; mi < 2; ++mi) {
        acc[mi][0] = __builtin_amdgcn_mfma_f32_16x16x32_bf16(aq[mi][ks], bk0, acc[mi][0], 0, 0, 0);
        acc[mi][1] = __builtin_amdgcn_mfma_f32_16x16x32_bf16(aq[mi][ks], bk1, acc[mi][1], 0, 0, 0);
      }
    }
#pragma unroll
    for (int ni = 0; ni < 2; ++ni) {
      const int col = k0 + ni * 16 + lr;
      const float lsv = LSg[b * NPAD + col];
#pragma unroll
      for (int mi = 0; mi < 2; ++mi)
#pragma unroll
        for (int j = 0; j < 4; ++j) {
          const int row = mi * 16 + lh * 4 + j;
          const int swcol = col ^ ((row & 7) << 3);
          Elds[row * ESTR + swcol] = f2bf(__expf(acc[mi][ni][j] * scale + lsv));
        }
    }
  }
  __syncthreads();

  const int qv = NN - q0;
  const int m = w & 1, kq = w >> 1;
  const f32x4 fz = {0.f, 0.f, 0.f, 0.f};
  f32x4 acc2[5];
#pragma unroll
  for (int ni = 0; ni < 5; ++ni) acc2[ni] = fz;

  // fused row-sum + normalized nt write (E kept in registers)
  auto norm_write = [&]() {
    const int r = tid >> 4, sub = tid & 15;
    const unsigned short* er = Elds + r * ESTR;
    const int sw = (r & 7) << 3;
    uint2 ev[12];
    float s = 0.f;
#pragma unroll
    for (int i = 0; i < 12; ++i) {
      const int col = i * 64 + sub * 4;
      if (col < NPAD) {
        ev[i] = *(const uint2*)(er + (col ^ sw));
        s += bf2f(ev[i].x & 0xffffu) + bf2f(ev[i].x >> 16) +
             bf2f(ev[i].y & 0xffffu) + bf2f(ev[i].y >> 16);
      }
    }
#pragma unroll
    for (int o = 1; o < 16; o <<= 1) s += __shfl_xor(s, o);
    const float inv = 1.f / s;
    if (sub == 0) INV[r] = inv;
    if (r < qv) {
      float* ao = attn_out + ((size_t)bh * NN + (q0 + r)) * NN;
#pragma unroll
      for (int i = 0; i < 12; ++i) {
        const int col = i * 64 + sub * 4;
        if (col + 4 <= NN) {
          f32x4 o;
          o[0] = bf2f(ev[i].x & 0xffffu) * inv;
          o[1] = bf2f(ev[i].x >> 16) * inv;
          o[2] = bf2f(ev[i].y & 0xffffu) * inv;
          o[3] = bf2f(ev[i].y >> 16) * inv;
          __builtin_nontemporal_store(o, (f32x4*)(ao + col));
        } else if (col < NN) {
          __builtin_nontemporal_store(bf2f(ev[i].x & 0xffffu) * inv, ao + col);  // col == 728
        }
      }
    }
  };

  // PV with tiled V (1KB contiguous B-frags) + double buffer
  auto pv = [&]() {
    const int kt0 = kq * 6, kt1 = (kq == 3) ? 23 : kt0 + 6;
    const unsigned short* vbase = Vv + (size_t)bh * 58880 + (lr * 32 + lh * 8);
    const int row = m * 16 + lr;
    const int sw = (row & 7) << 3;
    const unsigned short* erow = Elds + row * ESTR;
    bf16x8 vA[5], vB[5];
#pragma unroll
    for (int ni = 0; ni < 5; ++ni) vA[ni] = *(const bf16x8*)(vbase + (kt0 * 5 + ni) * 512);
    for (int kt = kt0; kt < kt1; kt += 2) {
      const bool h1 = (kt + 1 < kt1);
      if (h1) {
#pragma unroll
        for (int ni = 0; ni < 5; ++ni) vB[ni] = *(const bf16x8*)(vbase + ((kt + 1) * 5 + ni) * 512);
      }
      {
        const int k0 = kt * 32;
        const bf16x8 ap = *(const bf16x8*)(erow + ((k0 + lh * 8) ^ sw));
#pragma unroll
        for (int ni = 0; ni < 5; ++ni)
          acc2[ni] = __builtin_amdgcn_mfma_f32_16x16x32_bf16(ap, vA[ni], acc2[ni], 0, 0, 0);
      }
      if (h1) {
        if (kt + 2 < kt1) {
#pragma unroll
          for (int ni = 0; ni < 5; ++ni) vA[ni] = *(const bf16x8*)(vbase + ((kt + 2) * 5 + ni) * 512);
        }
        const int k0 = (kt + 1) * 32;
        const bf16x8 ap = *(const bf16x8*)(erow + ((k0 + lh * 8) ^ sw));
#pragma unroll
        for (int ni = 0; ni < 5; ++ni)
          acc2[ni] = __builtin_amdgcn_mfma_f32_16x16x32_bf16(ap, vB[ni], acc2[ni], 0, 0, 0);
      }
    }
  };

  // bh-parity stagger: half the WGs write first, half compute first
  if (bh & 1) {
    norm_write();
    pv();
  } else {
    pv();
    norm_write();
  }
  __syncthreads();

  if (kq > 0) {
    float* rd = red + ((kq - 1) * 2 + m) * 1344;
#pragma unroll
    for (int ni = 0; ni < 5; ++ni)
#pragma unroll
      for (int j = 0; j < 4; ++j)
        rd[(lh * 4 + j) * 84 + ni * 16 + lr] = acc2[ni][j];
  }
  __syncthreads();
  if (kq == 0) {
#pragma unroll
    for (int ni = 0; ni < 5; ++ni) {
      const int d = ni * 16 + lr;
      if (d < HDIM) {
#pragma unroll
        for (int j = 0; j < 4; ++j) {
          const int rrow = m * 16 + lh * 4 + j;
          const int q = q0 + rrow;
          if (q < NN) {
            const int ro = (lh * 4 + j) * 84 + ni * 16 + lr;
            const float s2 = acc2[ni][j] + red[m * 1344 + ro] + red[(2 + m) * 1344 + ro] +
                             red[(4 + m) * 1344 + ro];
            Ab[((size_t)b * NN + q) * DD + hh * HDIM + d] = f2bf(s2 * INV[rrow]);
          }
        }
      }
    }
  }
}

extern "C" void kernel_launch(void* const* d_in, const int* in_sizes, int n_in,
                              void* d_out, int out_size, void* d_ws, size_t ws_size,
                              hipStream_t stream) {
  const float* X = (const float*)d_in[0];
  const float* sz = (const float*)d_in[1];
  const float* Wq = (const float*)d_in[2];
  const float* bq = (const float*)d_in[3];
  const float* Wk = (const float*)d_in[4];
  const float* bk = (const float*)d_in[5];
  const float* Wv = (const float*)d_in[6];
  const float* bv = (const float*)d_in[7];
  const float* Wo = (const float*)d_in[8];
  const float* bo = (const float*)d_in[9];

  char* ws = (char*)d_ws;
  unsigned short* Xb = (unsigned short*)ws;                  // 11664x1152 bf16
  unsigned short* Wb = (unsigned short*)(ws + 26873856);     // 4x(1152x1152) bf16
  unsigned short* Qb = (unsigned short*)(ws + 37490688);     // (16,16,736,96)
  unsigned short* Kb = (unsigned short*)(ws + 73666560);     // (16,16,736,96)
  unsigned short* Vv = (unsigned short*)(ws + 109842432);    // (256,23,5,512) tiled V
  unsigned short* Ab = (unsigned short*)(ws + 146018304);    // 11664x1152 bf16
  unsigned short* Vtmp = Ab;                                 // V row-major (dead before attn)
  float* LSg = (float*)(ws + 172892160);                     // (16,736) fp32, dedicated

  float* out = (float*)d_out;
  float* attn = out + 13436928;
  float* metric = out + 149485824;

  prep_kernel<<<2048, 256, 0, stream>>>(X, Wq, Wk, Wv, Wo, sz, Xb, Wb, LSg);

  gemm8_kernel<0><<<644, 512, 0, stream>>>(Xb, Wb, bq, bk, bv, Qb, Kb, Vtmp, nullptr, 46, 3455);

  post_kernel<<<8192, 256, 0, stream>>>(Vtmp, Vv, Qb, Kb, metric);

  attn_kernel<<<5888, 512, 0, stream>>>(Qb, Kb, Vv, LSg, attn, Ab);

  gemm8_kernel<1><<<230, 512, 0, stream>>>(Ab, Wb + (size_t)3456 * 1152, bo, nullptr, nullptr,
                                           nullptr, nullptr, nullptr, out, 46, 1151);
}